// Round 1
// baseline (918.491 us; speedup 1.0000x reference)
//
#include <hip/hip_runtime.h>
#include <stdint.h>
#include <stddef.h>

#define NH 32
#define HD 128
#define HID 4096
#define QLEN 2048
#define KBLEN 1024
#define NTOPK 128
#define KVLEN 2176   // NTOPK + QLEN
#define PADV -1e9f
#define SCALE 0.08838834764831845f

typedef __attribute__((ext_vector_type(4))) float f32x4;
typedef __attribute__((ext_vector_type(4))) unsigned short u16x4;
typedef __attribute__((ext_vector_type(8))) short s16x8;

typedef const __attribute__((address_space(1))) void* gas1_t;
typedef __attribute__((address_space(3))) void* las3_t;

__device__ __forceinline__ void gload_lds16(const void* g, void* l) {
  __builtin_amdgcn_global_load_lds((gas1_t)g, (las3_t)l, 16, 0, 0);
}

__device__ __forceinline__ unsigned short f2bf(float x) {
  union { float f; unsigned u; } z; z.f = x;
  unsigned r = z.u + 0x7fffu + ((z.u >> 16) & 1u);
  return (unsigned short)(r >> 16);
}

// ---------------- small prep kernels ----------------

__global__ void k_cast(const float* __restrict__ src, unsigned short* __restrict__ dst, int n4) {
  int i = blockIdx.x * 256 + threadIdx.x;
  if (i >= n4) return;
  f32x4 v = ((const f32x4*)src)[i];
  u16x4 o;
  o[0] = f2bf(v[0]); o[1] = f2bf(v[1]); o[2] = f2bf(v[2]); o[3] = f2bf(v[3]);
  ((u16x4*)dst)[i] = o;
}

__global__ void k_rowsum(const float* __restrict__ x, float* __restrict__ out) {
  int d = blockIdx.x * 256 + threadIdx.x;
  float acc = 0.f;
  for (int q = 0; q < QLEN; ++q) acc += x[(size_t)q * HID + d];
  out[d] = acc;
}

// out[n] = s * dot(vec, mat[n,:]) ; one wave per n, 4 waves/block
__global__ void k_dotrows(const float* __restrict__ vec, const float* __restrict__ mat,
                          float* __restrict__ out, int K, float s) {
  int n = blockIdx.x * 4 + (threadIdx.x >> 6);
  int lane = threadIdx.x & 63;
  const float* row = mat + (size_t)n * K;
  float acc = 0.f;
  for (int j = lane; j < K; j += 64) acc += vec[j] * row[j];
#pragma unroll
  for (int off = 32; off > 0; off >>= 1) acc += __shfl_down(acc, off, 64);
  if (lane == 0) out[n] = acc * s;
}

// stable top-k by rank counting (tie-break: lower index wins, matches lax.top_k)
__global__ void k_topk(const float* __restrict__ scores, int* __restrict__ idx) {
  __shared__ float s[KBLEN];
  int t = threadIdx.x;
  s[t] = scores[t];
  __syncthreads();
  float mine = s[t];
  int rank = 0;
  for (int j = 0; j < KBLEN; ++j) {
    float v = s[j];
    rank += (v > mine) || (v == mine && j < t);
  }
  if (rank < NTOPK) idx[rank] = t;
}

// cos/sin table: cs[p*128 + i] = cos(pos_p * invf_i), cs[p*128+64+i] = sin(...)
__global__ void k_cs(const int* __restrict__ pos_ids, float* __restrict__ cs) {
  int t = blockIdx.x * 256 + threadIdx.x;   // QLEN*64 threads
  int p = t >> 6, i = t & 63;
  float pos = (float)pos_ids[p];
  float invf = powf(10000.0f, -(float)i / 64.0f);
  float a = pos * invf;
  cs[p * 128 + i] = cosf(a);
  cs[p * 128 + 64 + i] = sinf(a);
}

// rope: raw fp32 [q][4096] -> bf16 head layout dst[h][RO+q][128]
__global__ void k_rope(const float* __restrict__ raw, const float* __restrict__ cs,
                       unsigned short* __restrict__ dst, int RH, int RO) {
  int t = blockIdx.x * 256 + threadIdx.x;   // QLEN*NH*64 threads
  int i = t & 63;
  int hh = (t >> 6) & 31;
  int q = t >> 11;
  float x1 = raw[(size_t)q * HID + hh * HD + i];
  float x2 = raw[(size_t)q * HID + hh * HD + 64 + i];
  float c = cs[q * 128 + i];
  float sn = cs[q * 128 + 64 + i];
  size_t base = ((size_t)hh * RH + RO + q) * HD;
  dst[base + i]      = f2bf(x1 * c - x2 * sn);
  dst[base + 64 + i] = f2bf(x2 * c + x1 * sn);
}

// gather selected KB rows into k_all[:, :128] / v_all[:, :128]
__global__ void k_gather(const float* __restrict__ kbk, const float* __restrict__ kbv,
                         const int* __restrict__ idx,
                         unsigned short* __restrict__ kall, unsigned short* __restrict__ vall) {
  int t = blockIdx.x * 256 + threadIdx.x;   // NH*NTOPK*HD threads
  int d = t & 127;
  int i = (t >> 7) & 127;
  int hh = t >> 14;
  int kr = idx[i];
  size_t src = (size_t)kr * HID + hh * HD + d;
  size_t dstoff = ((size_t)hh * KVLEN + i) * HD + d;
  kall[dstoff] = f2bf(kbk[src]);
  vall[dstoff] = f2bf(kbv[src]);
}

// ---------------- bf16 MFMA GEMM: C[m,n] = sum_k A[m,k]*B[n,k] ----------------
// m97 structure: 128x128 tile, BK=64, 4 waves (2x2 of 64x64), global_load_lds w16.
// MODE 0: fp32 row-major Cf[m*N+n]. MODE 1: bf16 head layout Cb[h][RO+m][d], h=n>>7.
template<int MODE>
__global__ __launch_bounds__(256)
void gemm_bt(const unsigned short* __restrict__ A, const unsigned short* __restrict__ B,
             float* __restrict__ Cf, unsigned short* __restrict__ Cb,
             int M, int N, int K, int RH, int RO) {
  __shared__ unsigned short As[128 * 64];
  __shared__ unsigned short Bs[128 * 64];
  const int tid = threadIdx.x;
  const int lane = tid & 63;
  const int wave = tid >> 6;
  const int m0 = blockIdx.y * 128;
  const int n0 = blockIdx.x * 128;
  const int wm = wave >> 1, wn = wave & 1;

  f32x4 acc[4][4] = {};

  const int srow = tid >> 3;        // 0..31
  const int scol = (tid & 7) * 8;   // 0..56
  const unsigned ldsbase = wave * 512;  // elems

  for (int kt = 0; kt < K; kt += 64) {
    __syncthreads();
#pragma unroll
    for (int j = 0; j < 4; ++j) {
      gload_lds16(A + (size_t)(m0 + j * 32 + srow) * K + kt + scol, (void*)(As + j * 2048 + ldsbase));
      gload_lds16(B + (size_t)(n0 + j * 32 + srow) * K + kt + scol, (void*)(Bs + j * 2048 + ldsbase));
    }
    __syncthreads();
#pragma unroll
    for (int kk = 0; kk < 2; ++kk) {
      s16x8 a[4], b[4];
#pragma unroll
      for (int i = 0; i < 4; ++i)
        a[i] = *(const s16x8*)(As + (wm * 64 + i * 16 + (lane & 15)) * 64 + kk * 32 + (lane >> 4) * 8);
#pragma unroll
      for (int j = 0; j < 4; ++j)
        b[j] = *(const s16x8*)(Bs + (wn * 64 + j * 16 + (lane & 15)) * 64 + kk * 32 + (lane >> 4) * 8);
#pragma unroll
      for (int i = 0; i < 4; ++i)
#pragma unroll
        for (int j = 0; j < 4; ++j)
          acc[i][j] = __builtin_amdgcn_mfma_f32_16x16x32_bf16(a[i], b[j], acc[i][j], 0, 0, 0);
    }
  }

#pragma unroll
  for (int i = 0; i < 4; ++i) {
#pragma unroll
    for (int j = 0; j < 4; ++j) {
#pragma unroll
      for (int r = 0; r < 4; ++r) {
        int row = m0 + wm * 64 + i * 16 + (lane >> 4) * 4 + r;   // C/D: row=(l>>4)*4+reg
        int col = n0 + wn * 64 + j * 16 + (lane & 15);           //      col=l&15  [m89]
        float v = acc[i][j][r];
        if (MODE == 0) {
          Cf[(size_t)row * N + col] = v;
        } else {
          int hh = col >> 7, d = col & 127;
          Cb[((size_t)hh * RH + RO + row) * HD + d] = f2bf(v);
        }
      }
    }
  }
}

// ---------------- flash attention: block = (head, 64 q-rows), 4 waves x 16 rows ----------------
__global__ __launch_bounds__(256)
void attn_kernel(const unsigned short* __restrict__ qh,
                 const unsigned short* __restrict__ kall,
                 const unsigned short* __restrict__ vall,
                 const float* __restrict__ sshift,
                 unsigned short* __restrict__ ctx) {
  __shared__ unsigned short Ks[32 * 128];     // XOR-swizzled rows (G4: 256B rows are 16-way else)
  __shared__ unsigned short Vt[128 * 40];     // transposed, padded to 40 (80B rows, 16B-aligned)
  __shared__ unsigned short Plds[4][16 * 40]; // per-wave P tile, padded rows

  const int h = blockIdx.y;
  const int m0 = blockIdx.x * 64;
  const int tid = threadIdx.x;
  const int lane = tid & 63;
  const int wave = tid >> 6;
  const float shift = sshift[h];

  const unsigned short* kb = kall + (size_t)h * KVLEN * HD;
  const unsigned short* vb = vall + (size_t)h * KVLEN * HD;

  // Q fragments (A-op: row = lane&15, k = (lane>>4)*8 + i), hoisted
  s16x8 qf[4];
  {
    const unsigned short* qp = qh + ((size_t)h * QLEN + m0 + wave * 16 + (lane & 15)) * HD + (lane >> 4) * 8;
#pragma unroll
    for (int kc = 0; kc < 4; ++kc) qf[kc] = *(const s16x8*)(qp + kc * 32);
  }

  float m_run[4], l_run[4];
#pragma unroll
  for (int r = 0; r < 4; ++r) { m_run[r] = -1e30f; l_run[r] = 0.f; }
  f32x4 o[8] = {};

  const int nt = m0 / 32 + 6;  // 4 KB tiles + causal tiles up to row m0+63
  const int qrow_base = m0 + wave * 16 + (lane >> 4) * 4;

  for (int kt = 0; kt < nt; ++kt) {
    __syncthreads();
    // stage K tile (32x128), swizzled: LDS[row][cb] = K[row][cb ^ ((row&7)<<4)]
#pragma unroll
    for (int it = 0; it < 2; ++it) {
      int c = it * 256 + tid;
      int row = c >> 4;
      int cb = (c & 15) << 4;
      int scb = cb ^ ((row & 7) << 4);
      s16x8 kv = *(const s16x8*)(kb + (size_t)(kt * 32 + row) * HD + (scb >> 1));
      *(s16x8*)((char*)Ks + row * 256 + cb) = kv;
    }
    // stage V transposed: Vt[d][r], u32 pair writes (r0, r0+1)
#pragma unroll
    for (int j = 0; j < 8; ++j) {
      int pi = j * 256 + tid;        // 0..2047
      int d = pi & 127;
      int r0 = (pi >> 7) * 2;        // 0,2,..,30
      unsigned short v0 = vb[(size_t)(kt * 32 + r0) * HD + d];
      unsigned short v1 = vb[(size_t)(kt * 32 + r0 + 1) * HD + d];
      *(unsigned*)(&Vt[d * 40 + r0]) = (unsigned)v0 | ((unsigned)v1 << 16);
    }
    __syncthreads();

    // S = Q K^T (16 q-rows x 32 keys), accumulate over 4 k-chunks
    f32x4 s0 = {}, s1 = {};
    int key0 = lane & 15;
    int key1 = 16 + key0;
#pragma unroll
    for (int kc = 0; kc < 4; ++kc) {
      int inner = kc * 64 + (lane >> 4) * 16;
      s16x8 kf0 = *(const s16x8*)((const char*)Ks + key0 * 256 + (inner ^ ((key0 & 7) << 4)));
      s16x8 kf1 = *(const s16x8*)((const char*)Ks + key1 * 256 + (inner ^ ((key1 & 7) << 4)));
      s0 = __builtin_amdgcn_mfma_f32_16x16x32_bf16(qf[kc], kf0, s0, 0, 0, 0);
      s1 = __builtin_amdgcn_mfma_f32_16x16x32_bf16(qf[kc], kf1, s1, 0, 0, 0);
    }

    // scale + shift/causal-mask, per-row online softmax
    float sv0[4], sv1[4], mx[4];
    int k0i = kt * 32 + key0;
    int k1i = k0i + 16;
#pragma unroll
    for (int r = 0; r < 4; ++r) {
      int mrow = qrow_base + r;
      float v0 = s0[r] * SCALE;
      float v1 = s1[r] * SCALE;
      v0 = (k0i < NTOPK) ? (v0 + shift) : ((k0i - NTOPK > mrow) ? PADV : v0);
      v1 = (k1i < NTOPK) ? (v1 + shift) : ((k1i - NTOPK > mrow) ? PADV : v1);
      sv0[r] = v0; sv1[r] = v1;
      mx[r] = fmaxf(v0, v1);
    }
#pragma unroll
    for (int off = 1; off < 16; off <<= 1) {
#pragma unroll
      for (int r = 0; r < 4; ++r) mx[r] = fmaxf(mx[r], __shfl_xor(mx[r], off, 64));
    }
    float alpha[4], rs[4];
#pragma unroll
    for (int r = 0; r < 4; ++r) {
      float mn = fmaxf(m_run[r], mx[r]);
      alpha[r] = __expf(m_run[r] - mn);
      m_run[r] = mn;
      float p0 = __expf(sv0[r] - mn);
      float p1 = __expf(sv1[r] - mn);
      rs[r] = p0 + p1;
      int qr = (lane >> 4) * 4 + r;
      Plds[wave][qr * 40 + key0] = f2bf(p0);
      Plds[wave][qr * 40 + 16 + key0] = f2bf(p1);
    }
#pragma unroll
    for (int off = 1; off < 16; off <<= 1) {
#pragma unroll
      for (int r = 0; r < 4; ++r) rs[r] += __shfl_xor(rs[r], off, 64);
    }
#pragma unroll
    for (int r = 0; r < 4; ++r) l_run[r] = l_run[r] * alpha[r] + rs[r];
#pragma unroll
    for (int db = 0; db < 8; ++db)
#pragma unroll
      for (int r = 0; r < 4; ++r) o[db][r] *= alpha[r];

    // PV: A = P[q][key] from Plds, B = V[key][d] from Vt
    s16x8 pf = *(const s16x8*)(&Plds[wave][(lane & 15) * 40 + (lane >> 4) * 8]);
#pragma unroll
    for (int db = 0; db < 8; ++db) {
      s16x8 vf = *(const s16x8*)((const char*)Vt + (db * 16 + (lane & 15)) * 80 + (lane >> 4) * 16);
      o[db] = __builtin_amdgcn_mfma_f32_16x16x32_bf16(pf, vf, o[db], 0, 0, 0);
    }
  }

  // normalize + write ctx[q][h*128+d] bf16
#pragma unroll
  for (int db = 0; db < 8; ++db) {
#pragma unroll
    for (int r = 0; r < 4; ++r) {
      int row = qrow_base + r;
      int col = h * HD + db * 16 + (lane & 15);
      ctx[(size_t)row * HID + col] = f2bf(o[db][r] / l_run[r]);
    }
  }
}

// ---------------- launch ----------------

extern "C" void kernel_launch(void* const* d_in, const int* in_sizes, int n_in,
                              void* d_out, int out_size, void* d_ws, size_t ws_size,
                              hipStream_t stream) {
  const float* hidden    = (const float*)d_in[0];
  // d_in[1] attention_mask: pure causal by construction — implemented analytically
  const int*   pos       = (const int*)d_in[2];
  const float* kb_keys   = (const float*)d_in[3];
  const float* kb_values = (const float*)d_in[4];
  const float* Wq        = (const float*)d_in[5];
  const float* Wq2       = (const float*)d_in[6];
  const float* Wk        = (const float*)d_in[7];
  const float* Wv        = (const float*)d_in[8];
  const float* Wo        = (const float*)d_in[9];
  const float* sshift    = (const float*)d_in[10];
  float* out = (float*)d_out;

  char* ws = (char*)d_ws;
  size_t off = 0;
  auto alloc = [&](size_t bytes) { char* p = ws + off; off += (bytes + 255) & ~(size_t)255; return p; };
  unsigned short* hidden_bf = (unsigned short*)alloc((size_t)QLEN * HID * 2);
  unsigned short* wbuf      = (unsigned short*)alloc((size_t)HID * HID * 2);
  float*          qraw      = (float*)alloc((size_t)QLEN * HID * 4);
  float*          kraw      = (float*)alloc((size_t)QLEN * HID * 4);
  unsigned short* qbf       = (unsigned short*)alloc((size_t)NH * QLEN * HD * 2);
  unsigned short* kallp     = (unsigned short*)alloc((size_t)NH * KVLEN * HD * 2);
  unsigned short* vallp     = (unsigned short*)alloc((size_t)NH * KVLEN * HD * 2);
  unsigned short* ctx       = (unsigned short*)alloc((size_t)QLEN * HID * 2);
  float*          cs        = (float*)alloc((size_t)QLEN * 128 * 4);
  float*          hsum      = (float*)alloc(HID * 4);
  float*          qs        = (float*)alloc(HID * 4);
  float*          scores    = (float*)alloc(KBLEN * 4);
  int*            idx       = (int*)alloc(NTOPK * 4);

  dim3 blk(256);

  // prep: cast hidden, top-k scoring path (fp32 end-to-end), rope table
  k_cast<<<QLEN * HID / 4 / 256, blk, 0, stream>>>(hidden, hidden_bf, QLEN * HID / 4);
  k_rowsum<<<HID / 256, blk, 0, stream>>>(hidden, hsum);
  k_dotrows<<<HID / 4, blk, 0, stream>>>(hsum, Wq2, qs, HID, 1.0f);
  k_dotrows<<<KBLEN / 4, blk, 0, stream>>>(qs, kb_keys, scores, HID, SCALE);
  k_topk<<<1, KBLEN, 0, stream>>>(scores, idx);
  k_cs<<<QLEN * 64 / 256, blk, 0, stream>>>(pos, cs);

  dim3 ggrid(HID / 128, QLEN / 128);  // (32, 16)
  int wcast_blocks = HID * HID / 4 / 256;

  // Q projection -> qraw (fp32)
  k_cast<<<wcast_blocks, blk, 0, stream>>>(Wq, wbuf, HID * HID / 4);
  gemm_bt<0><<<ggrid, blk, 0, stream>>>(hidden_bf, wbuf, qraw, nullptr, QLEN, HID, HID, 0, 0);
  // K projection -> kraw (fp32)
  k_cast<<<wcast_blocks, blk, 0, stream>>>(Wk, wbuf, HID * HID / 4);
  gemm_bt<0><<<ggrid, blk, 0, stream>>>(hidden_bf, wbuf, kraw, nullptr, QLEN, HID, HID, 0, 0);
  // V projection -> v_all[h][128+q][d] (bf16)
  k_cast<<<wcast_blocks, blk, 0, stream>>>(Wv, wbuf, HID * HID / 4);
  gemm_bt<1><<<ggrid, blk, 0, stream>>>(hidden_bf, wbuf, nullptr, vallp, QLEN, HID, HID, KVLEN, NTOPK);

  // rope -> head layouts
  k_rope<<<QLEN * NH * 64 / 256, blk, 0, stream>>>(qraw, cs, qbf, QLEN, 0);
  k_rope<<<QLEN * NH * 64 / 256, blk, 0, stream>>>(kraw, cs, kallp, KVLEN, NTOPK);

  // gather selected KB keys/values into k_all/v_all[:, :128]
  k_gather<<<NH * NTOPK * HD / 256, blk, 0, stream>>>(kb_keys, kb_values, idx, kallp, vallp);

  // flash attention -> ctx bf16 [q][h*128+d]
  dim3 agrid(QLEN / 64, NH);  // (32, 32)
  attn_kernel<<<agrid, blk, 0, stream>>>(qbf, kallp, vallp, sshift, ctx);

  // output projection -> d_out fp32
  k_cast<<<wcast_blocks, blk, 0, stream>>>(Wo, wbuf, HID * HID / 4);
  gemm_bt<0><<<ggrid, blk, 0, stream>>>(ctx, wbuf, out, nullptr, QLEN, HID, HID, 0, 0);
}

// Round 2
// 715.637 us; speedup vs baseline: 1.2835x; 1.2835x over previous
//
#include <hip/hip_runtime.h>
#include <stdint.h>
#include <stddef.h>

#define NH 32
#define HD 128
#define HID 4096
#define QLEN 2048
#define KBLEN 1024
#define NTOPK 128
#define KVLEN 2176   // NTOPK + QLEN
#define PADV -1e9f
#define SCALE 0.08838834764831845f

typedef __attribute__((ext_vector_type(4))) float f32x4;
typedef __attribute__((ext_vector_type(4))) unsigned short u16x4;
typedef __attribute__((ext_vector_type(8))) short s16x8;
typedef __attribute__((ext_vector_type(4))) short s16x4;

typedef const __attribute__((address_space(1))) void* gas1_t;
typedef __attribute__((address_space(3))) void* las3_t;

__device__ __forceinline__ void gload_lds16(const void* g, void* l) {
  __builtin_amdgcn_global_load_lds((gas1_t)g, (las3_t)l, 16, 0, 0);
}

__device__ __forceinline__ unsigned short f2bf(float x) {
  union { float f; unsigned u; } z; z.f = x;
  unsigned r = z.u + 0x7fffu + ((z.u >> 16) & 1u);
  return (unsigned short)(r >> 16);
}

// hardware transpose read: lane gets column (addr&127)/8 of the 128B-aligned
// [4 rows][16 cols] bf16 subtile containing addr  [m156/m162 model]
__device__ __forceinline__ s16x4 tr16(unsigned addr) {
  s16x4 r;
  asm volatile("ds_read_b64_tr_b16 %0, %1" : "=v"(r) : "v"(addr));
  return r;
}

__device__ __forceinline__ s16x8 cat8(s16x4 a, s16x4 b) {
  s16x8 r;
  r[0]=a[0]; r[1]=a[1]; r[2]=a[2]; r[3]=a[3];
  r[4]=b[0]; r[5]=b[1]; r[6]=b[2]; r[7]=b[3];
  return r;
}

// ---------------- small prep kernels ----------------

__global__ void k_cast(const float* __restrict__ src, unsigned short* __restrict__ dst, int n4) {
  int i = blockIdx.x * 256 + threadIdx.x;
  if (i >= n4) return;
  f32x4 v = ((const f32x4*)src)[i];
  u16x4 o;
  o[0] = f2bf(v[0]); o[1] = f2bf(v[1]); o[2] = f2bf(v[2]); o[3] = f2bf(v[3]);
  ((u16x4*)dst)[i] = o;
}

// column sums of hidden: two-stage, deterministic (no atomics -> top-k stable)
__global__ void k_rowsum_p(const float* __restrict__ x, float* __restrict__ part) {
  int d = blockIdx.x * 256 + threadIdx.x;
  int q0 = blockIdx.y * 128;
  float acc = 0.f;
  for (int q = q0; q < q0 + 128; ++q) acc += x[(size_t)q * HID + d];
  part[(size_t)blockIdx.y * HID + d] = acc;
}
__global__ void k_rowsum_r(const float* __restrict__ part, float* __restrict__ out) {
  int d = blockIdx.x * 256 + threadIdx.x;
  float acc = 0.f;
#pragma unroll
  for (int i = 0; i < 16; ++i) acc += part[(size_t)i * HID + d];
  out[d] = acc;
}

// out[n] = s * dot(vec, mat[n,:]) ; one wave per n, 4 waves/block
__global__ void k_dotrows(const float* __restrict__ vec, const float* __restrict__ mat,
                          float* __restrict__ out, int K, float s) {
  int n = blockIdx.x * 4 + (threadIdx.x >> 6);
  int lane = threadIdx.x & 63;
  const float* row = mat + (size_t)n * K;
  float acc = 0.f;
  for (int j = lane; j < K; j += 64) acc += vec[j] * row[j];
#pragma unroll
  for (int off = 32; off > 0; off >>= 1) acc += __shfl_down(acc, off, 64);
  if (lane == 0) out[n] = acc * s;
}

// stable top-k by rank counting (tie-break: lower index wins, matches lax.top_k)
__global__ void k_topk(const float* __restrict__ scores, int* __restrict__ idx) {
  __shared__ float s[KBLEN];
  int t = threadIdx.x;
  s[t] = scores[t];
  __syncthreads();
  float mine = s[t];
  int rank = 0;
  for (int j = 0; j < KBLEN; ++j) {
    float v = s[j];
    rank += (v > mine) || (v == mine && j < t);
  }
  if (rank < NTOPK) idx[rank] = t;
}

// cos/sin table: cs[p*128 + i] = cos(pos_p * invf_i), cs[p*128+64+i] = sin(...)
__global__ void k_cs(const int* __restrict__ pos_ids, float* __restrict__ cs) {
  int t = blockIdx.x * 256 + threadIdx.x;   // QLEN*64 threads
  int p = t >> 6, i = t & 63;
  float pos = (float)pos_ids[p];
  float invf = powf(10000.0f, -(float)i / 64.0f);
  float a = pos * invf;
  cs[p * 128 + i] = cosf(a);
  cs[p * 128 + 64 + i] = sinf(a);
}

// rope: raw fp32 [q][4096] -> bf16 head layout dst[h][RO+q][128]
__global__ void k_rope(const float* __restrict__ raw, const float* __restrict__ cs,
                       unsigned short* __restrict__ dst, int RH, int RO) {
  int t = blockIdx.x * 256 + threadIdx.x;   // QLEN*NH*64 threads
  int i = t & 63;
  int hh = (t >> 6) & 31;
  int q = t >> 11;
  float x1 = raw[(size_t)q * HID + hh * HD + i];
  float x2 = raw[(size_t)q * HID + hh * HD + 64 + i];
  float c = cs[q * 128 + i];
  float sn = cs[q * 128 + 64 + i];
  size_t base = ((size_t)hh * RH + RO + q) * HD;
  dst[base + i]      = f2bf(x1 * c - x2 * sn);
  dst[base + 64 + i] = f2bf(x2 * c + x1 * sn);
}

// gather selected KB rows into k_all[:, :128] / v_all[:, :128]
__global__ void k_gather(const float* __restrict__ kbk, const float* __restrict__ kbv,
                         const int* __restrict__ idx,
                         unsigned short* __restrict__ kall, unsigned short* __restrict__ vall) {
  int t = blockIdx.x * 256 + threadIdx.x;   // NH*NTOPK*HD threads
  int d = t & 127;
  int i = (t >> 7) & 127;
  int hh = t >> 14;
  int kr = idx[i];
  size_t src = (size_t)kr * HID + hh * HD + d;
  size_t dstoff = ((size_t)hh * KVLEN + i) * HD + d;
  kall[dstoff] = f2bf(kbk[src]);
  vall[dstoff] = f2bf(kbv[src]);
}

// ---------------- bf16 MFMA GEMM: C[m,n] = sum_k A[m,k]*B[n,k] ----------------
// m97 structure: 128x128 tile, BK=64, 4 waves (2x2 of 64x64), global_load_lds w16.
// MODE 0: fp32 row-major Cf[m*N+n]. MODE 1: bf16 head layout Cb[h][RO+m][d], h=n>>7.
template<int MODE>
__global__ __launch_bounds__(256)
void gemm_bt(const unsigned short* __restrict__ A, const unsigned short* __restrict__ B,
             float* __restrict__ Cf, unsigned short* __restrict__ Cb,
             int M, int N, int K, int RH, int RO) {
  __shared__ unsigned short As[128 * 64];
  __shared__ unsigned short Bs[128 * 64];
  const int tid = threadIdx.x;
  const int lane = tid & 63;
  const int wave = tid >> 6;
  const int m0 = blockIdx.y * 128;
  const int n0 = blockIdx.x * 128;
  const int wm = wave >> 1, wn = wave & 1;

  f32x4 acc[4][4] = {};

  const int srow = tid >> 3;        // 0..31
  const int scol = (tid & 7) * 8;   // 0..56
  const unsigned ldsbase = wave * 512;  // elems

  for (int kt = 0; kt < K; kt += 64) {
    __syncthreads();
#pragma unroll
    for (int j = 0; j < 4; ++j) {
      gload_lds16(A + (size_t)(m0 + j * 32 + srow) * K + kt + scol, (void*)(As + j * 2048 + ldsbase));
      gload_lds16(B + (size_t)(n0 + j * 32 + srow) * K + kt + scol, (void*)(Bs + j * 2048 + ldsbase));
    }
    __syncthreads();
#pragma unroll
    for (int kk = 0; kk < 2; ++kk) {
      s16x8 a[4], b[4];
#pragma unroll
      for (int i = 0; i < 4; ++i)
        a[i] = *(const s16x8*)(As + (wm * 64 + i * 16 + (lane & 15)) * 64 + kk * 32 + (lane >> 4) * 8);
#pragma unroll
      for (int j = 0; j < 4; ++j)
        b[j] = *(const s16x8*)(Bs + (wn * 64 + j * 16 + (lane & 15)) * 64 + kk * 32 + (lane >> 4) * 8);
#pragma unroll
      for (int i = 0; i < 4; ++i)
#pragma unroll
        for (int j = 0; j < 4; ++j)
          acc[i][j] = __builtin_amdgcn_mfma_f32_16x16x32_bf16(a[i], b[j], acc[i][j], 0, 0, 0);
    }
  }

#pragma unroll
  for (int i = 0; i < 4; ++i) {
#pragma unroll
    for (int j = 0; j < 4; ++j) {
#pragma unroll
      for (int r = 0; r < 4; ++r) {
        int row = m0 + wm * 64 + i * 16 + (lane >> 4) * 4 + r;   // C/D: row=(l>>4)*4+reg
        int col = n0 + wn * 64 + j * 16 + (lane & 15);           //      col=l&15  [m89]
        float v = acc[i][j][r];
        if (MODE == 0) {
          Cf[(size_t)row * N + col] = v;
        } else {
          int hh = col >> 7, d = col & 127;
          Cb[((size_t)hh * RH + RO + row) * HD + d] = f2bf(v);
        }
      }
    }
  }
}

// ---------------- flash attention ----------------
// Block = (head, paired q-chunks {x, 31-x}) -> exactly 37 KV-tiles per block.
// 4 waves x 16 q-rows, KVBLK=64. K: row-major 16B-XOR-swizzled, staged by
// global_load_lds with pre-swizzled source. V: [kq][dc][4][16] subtiled for
// ds_read_b64_tr_b16 PV B-fragments. P: LDS stride 72 elems (144B).
__global__ __launch_bounds__(256)
void attn_kernel(const unsigned short* __restrict__ qh,
                 const unsigned short* __restrict__ kall,
                 const unsigned short* __restrict__ vall,
                 const float* __restrict__ sshift,
                 unsigned short* __restrict__ ctx) {
  __shared__ __align__(1024) unsigned short Ks[64 * 128];
  __shared__ __align__(1024) unsigned short Vs[64 * 128];
  __shared__ __align__(16)  unsigned short Plds[4][16 * 72];

  // bijective XCD swizzle (m204): 512 wgs / 8 xcds -> 64-wg chunks = 4 heads/XCD
  int orig = blockIdx.y * 16 + blockIdx.x;
  int wgid = (orig & 7) * 64 + (orig >> 3);
  int h = wgid >> 4;
  int xch = wgid & 15;

  const int tid = threadIdx.x;
  const int lane = tid & 63;
  const int wave = tid >> 6;
  const int lo = lane & 15;
  const int hi = lane >> 4;
  const float shift = sshift[h];

  const unsigned short* kb = kall + (size_t)h * KVLEN * HD;
  const unsigned short* vb = vall + (size_t)h * KVLEN * HD;

  const unsigned vsb = (unsigned)(uintptr_t)(&Vs[0]);

#pragma unroll 1
  for (int half = 0; half < 2; ++half) {
    const int qc = half ? (31 - xch) : xch;
    const int m0 = qc * 64;

    s16x8 qf[4];
    {
      const unsigned short* qp = qh + ((size_t)h * QLEN + m0 + wave * 16 + lo) * HD + hi * 8;
#pragma unroll
      for (int kc = 0; kc < 4; ++kc) qf[kc] = *(const s16x8*)(qp + kc * 32);
    }

    float m_run[4], l_run[4];
#pragma unroll
    for (int r = 0; r < 4; ++r) { m_run[r] = -1e30f; l_run[r] = 0.f; }
    f32x4 o[8] = {};

    const int nt = qc + 3;                    // 2 KB tiles + (qc+1) causal tiles
    const int qrow = m0 + wave * 16 + hi * 4; // +r

    for (int kt = 0; kt < nt; ++kt) {
      const unsigned short* kg = kb + (size_t)kt * 64 * HD;
      const unsigned short* vg = vb + (size_t)kt * 64 * HD;
      __syncthreads();
      // stage K + V: 1024 16B chunks each, LDS dest linear, source permuted
#pragma unroll
      for (int it = 0; it < 4; ++it) {
        int j0 = it * 256 + wave * 64;     // wave-uniform base chunk
        int j = j0 + lane;
        // K: LDS[row][cb] = K[row][cb ^ (row&7)] (16B chunk units)
        int row = j >> 4, cb = j & 15;
        gload_lds16(kg + row * 128 + ((cb ^ (row & 7)) * 8), (void*)(Ks + j0 * 8));
        // V subtiled: dest chunk j = (kq,dc,kr,half) <- V[kq*4+kr][dc*16+half*8]
        int kq = j >> 6, dc = (j >> 3) & 7, kr = (j >> 1) & 3, hf = j & 1;
        gload_lds16(vg + (kq * 4 + kr) * 128 + dc * 16 + hf * 8, (void*)(Vs + j0 * 8));
      }
      __syncthreads();

      // S = Q K^T : 16 q-rows x 64 keys per wave
      f32x4 s[4] = {};
#pragma unroll
      for (int kc = 0; kc < 4; ++kc) {
#pragma unroll
        for (int g = 0; g < 4; ++g) {
          int key = g * 16 + lo;
          s16x8 kf = *(const s16x8*)(Ks + key * 128 + (((kc * 4 + hi) ^ (key & 7)) * 8));
          s[g] = __builtin_amdgcn_mfma_f32_16x16x32_bf16(qf[kc], kf, s[g], 0, 0, 0);
        }
      }

      // mask + online softmax
      const int kvbase = kt * 64;
      float sv[4][4], mx[4];
#pragma unroll
      for (int r = 0; r < 4; ++r) {
        int qr = qrow + r;
#pragma unroll
        for (int g = 0; g < 4; ++g) {
          int kv = kvbase + g * 16 + lo;
          float v = s[g][r] * SCALE;
          v = (kv < NTOPK) ? (v + shift) : ((kv - NTOPK > qr) ? PADV : v);
          sv[g][r] = v;
        }
        mx[r] = fmaxf(fmaxf(sv[0][r], sv[1][r]), fmaxf(sv[2][r], sv[3][r]));
      }
#pragma unroll
      for (int off = 1; off < 16; off <<= 1)
#pragma unroll
        for (int r = 0; r < 4; ++r) mx[r] = fmaxf(mx[r], __shfl_xor(mx[r], off, 64));

      float alpha[4], rs[4];
#pragma unroll
      for (int r = 0; r < 4; ++r) {
        float mn = fmaxf(m_run[r], mx[r]);
        alpha[r] = __expf(m_run[r] - mn);
        m_run[r] = mn;
        float acc = 0.f;
#pragma unroll
        for (int g = 0; g < 4; ++g) {
          float p = __expf(sv[g][r] - mn);
          acc += p;
          Plds[wave][(hi * 4 + r) * 72 + g * 16 + lo] = f2bf(p);
        }
        rs[r] = acc;
      }
#pragma unroll
      for (int off = 1; off < 16; off <<= 1)
#pragma unroll
        for (int r = 0; r < 4; ++r) rs[r] += __shfl_xor(rs[r], off, 64);
#pragma unroll
      for (int r = 0; r < 4; ++r) l_run[r] = l_run[r] * alpha[r] + rs[r];
#pragma unroll
      for (int db = 0; db < 8; ++db)
#pragma unroll
        for (int r = 0; r < 4; ++r) o[db][r] *= alpha[r];

      // PV: A = P (same-wave LDS round trip), B = V^T via tr16
      s16x8 pf0 = *(const s16x8*)(&Plds[wave][lo * 72 + hi * 8]);
      s16x8 pf1 = *(const s16x8*)(&Plds[wave][lo * 72 + 32 + hi * 8]);
      const unsigned vb0 = vsb + hi * 2048 + lo * 8;
#pragma unroll
      for (int dbp = 0; dbp < 4; ++dbp) {
        s16x4 t[2][2][2];
#pragma unroll
        for (int dbi = 0; dbi < 2; ++dbi) {
          unsigned a0 = vb0 + (dbp * 2 + dbi) * 128;
          t[dbi][0][0] = tr16(a0);
          t[dbi][0][1] = tr16(a0 + 1024);
          t[dbi][1][0] = tr16(a0 + 8192);
          t[dbi][1][1] = tr16(a0 + 8192 + 1024);
        }
        asm volatile("s_waitcnt lgkmcnt(0)" ::: "memory");
        __builtin_amdgcn_sched_barrier(0);   // rule #18: pin MFMA after the wait
#pragma unroll
        for (int dbi = 0; dbi < 2; ++dbi) {
          int db = dbp * 2 + dbi;
          o[db] = __builtin_amdgcn_mfma_f32_16x16x32_bf16(pf0, cat8(t[dbi][0][0], t[dbi][0][1]), o[db], 0, 0, 0);
          o[db] = __builtin_amdgcn_mfma_f32_16x16x32_bf16(pf1, cat8(t[dbi][1][0], t[dbi][1][1]), o[db], 0, 0, 0);
        }
      }
    } // kt

    // normalize + write ctx[q][h*128+d] bf16
#pragma unroll
    for (int db = 0; db < 8; ++db) {
#pragma unroll
      for (int r = 0; r < 4; ++r) {
        int row = qrow + r;
        int col = h * HD + db * 16 + lo;
        ctx[(size_t)row * HID + col] = f2bf(o[db][r] / l_run[r]);
      }
    }
  } // half
}

// ---------------- launch ----------------

extern "C" void kernel_launch(void* const* d_in, const int* in_sizes, int n_in,
                              void* d_out, int out_size, void* d_ws, size_t ws_size,
                              hipStream_t stream) {
  const float* hidden    = (const float*)d_in[0];
  // d_in[1] attention_mask: pure causal by construction — implemented analytically
  const int*   pos       = (const int*)d_in[2];
  const float* kb_keys   = (const float*)d_in[3];
  const float* kb_values = (const float*)d_in[4];
  const float* Wq        = (const float*)d_in[5];
  const float* Wq2       = (const float*)d_in[6];
  const float* Wk        = (const float*)d_in[7];
  const float* Wv        = (const float*)d_in[8];
  const float* Wo        = (const float*)d_in[9];
  const float* sshift    = (const float*)d_in[10];
  float* out = (float*)d_out;

  char* ws = (char*)d_ws;
  size_t off = 0;
  auto alloc = [&](size_t bytes) { char* p = ws + off; off += (bytes + 255) & ~(size_t)255; return p; };
  unsigned short* hidden_bf = (unsigned short*)alloc((size_t)QLEN * HID * 2);
  unsigned short* wbuf      = (unsigned short*)alloc((size_t)HID * HID * 2);
  float*          qraw      = (float*)alloc((size_t)QLEN * HID * 4);
  float*          kraw      = (float*)alloc((size_t)QLEN * HID * 4);
  unsigned short* qbf       = (unsigned short*)alloc((size_t)NH * QLEN * HD * 2);
  unsigned short* kallp     = (unsigned short*)alloc((size_t)NH * KVLEN * HD * 2);
  unsigned short* vallp     = (unsigned short*)alloc((size_t)NH * KVLEN * HD * 2);
  unsigned short* ctx       = (unsigned short*)alloc((size_t)QLEN * HID * 2);
  float*          cs        = (float*)alloc((size_t)QLEN * 128 * 4);
  float*          part      = (float*)alloc((size_t)16 * HID * 4);
  float*          hsum      = (float*)alloc(HID * 4);
  float*          qs        = (float*)alloc(HID * 4);
  float*          scores    = (float*)alloc(KBLEN * 4);
  int*            idx       = (int*)alloc(NTOPK * 4);

  dim3 blk(256);

  // prep: cast hidden, top-k scoring path (fp32 end-to-end), rope table
  k_cast<<<QLEN * HID / 4 / 256, blk, 0, stream>>>(hidden, hidden_bf, QLEN * HID / 4);
  k_rowsum_p<<<dim3(HID / 256, 16), blk, 0, stream>>>(hidden, part);
  k_rowsum_r<<<HID / 256, blk, 0, stream>>>(part, hsum);
  k_dotrows<<<HID / 4, blk, 0, stream>>>(hsum, Wq2, qs, HID, 1.0f);
  k_dotrows<<<KBLEN / 4, blk, 0, stream>>>(qs, kb_keys, scores, HID, SCALE);
  k_topk<<<1, KBLEN, 0, stream>>>(scores, idx);
  k_cs<<<QLEN * 64 / 256, blk, 0, stream>>>(pos, cs);

  dim3 ggrid(HID / 128, QLEN / 128);  // (32, 16)
  int wcast_blocks = HID * HID / 4 / 256;

  // Q projection -> qraw (fp32)
  k_cast<<<wcast_blocks, blk, 0, stream>>>(Wq, wbuf, HID * HID / 4);
  gemm_bt<0><<<ggrid, blk, 0, stream>>>(hidden_bf, wbuf, qraw, nullptr, QLEN, HID, HID, 0, 0);
  // K projection -> kraw (fp32)
  k_cast<<<wcast_blocks, blk, 0, stream>>>(Wk, wbuf, HID * HID / 4);
  gemm_bt<0><<<ggrid, blk, 0, stream>>>(hidden_bf, wbuf, kraw, nullptr, QLEN, HID, HID, 0, 0);
  // V projection -> v_all[h][128+q][d] (bf16)
  k_cast<<<wcast_blocks, blk, 0, stream>>>(Wv, wbuf, HID * HID / 4);
  gemm_bt<1><<<ggrid, blk, 0, stream>>>(hidden_bf, wbuf, nullptr, vallp, QLEN, HID, HID, KVLEN, NTOPK);

  // rope -> head layouts
  k_rope<<<QLEN * NH * 64 / 256, blk, 0, stream>>>(qraw, cs, qbf, QLEN, 0);
  k_rope<<<QLEN * NH * 64 / 256, blk, 0, stream>>>(kraw, cs, kallp, KVLEN, NTOPK);

  // gather selected KB keys/values into k_all/v_all[:, :128]
  k_gather<<<NH * NTOPK * HD / 256, blk, 0, stream>>>(kb_keys, kb_values, idx, kallp, vallp);

  // flash attention -> ctx bf16 [q][h*128+d]
  dim3 agrid(16, NH);  // paired q-chunks: 512 balanced blocks
  attn_kernel<<<agrid, blk, 0, stream>>>(qbf, kallp, vallp, sshift, ctx);

  // output projection -> d_out fp32
  k_cast<<<wcast_blocks, blk, 0, stream>>>(Wo, wbuf, HID * HID / 4);
  gemm_bt<0><<<ggrid, blk, 0, stream>>>(ctx, wbuf, out, nullptr, QLEN, HID, HID, 0, 0);
}

// Round 3
// 595.643 us; speedup vs baseline: 1.5420x; 1.2015x over previous
//
#include <hip/hip_runtime.h>
#include <stdint.h>
#include <stddef.h>

#define NH 32
#define HD 128
#define HID 4096
#define QLEN 2048
#define KBLEN 1024
#define NTOPK 128
#define KVLEN 2176   // NTOPK + QLEN
#define PADV -1e9f
#define SCALE 0.08838834764831845f

typedef __attribute__((ext_vector_type(4))) float f32x4;
typedef __attribute__((ext_vector_type(4))) unsigned short u16x4;
typedef __attribute__((ext_vector_type(8))) short s16x8;
typedef __attribute__((ext_vector_type(4))) short s16x4;

typedef const __attribute__((address_space(1))) void* gas1_t;
typedef __attribute__((address_space(3))) void* las3_t;

__device__ __forceinline__ void gload_lds16(const void* g, void* l) {
  __builtin_amdgcn_global_load_lds((gas1_t)g, (las3_t)l, 16, 0, 0);
}

__device__ __forceinline__ unsigned short f2bf(float x) {
  union { float f; unsigned u; } z; z.f = x;
  unsigned r = z.u + 0x7fffu + ((z.u >> 16) & 1u);
  return (unsigned short)(r >> 16);
}

// hardware transpose read [m156/m162 model]
__device__ __forceinline__ s16x4 tr16(unsigned addr) {
  s16x4 r;
  asm volatile("ds_read_b64_tr_b16 %0, %1" : "=v"(r) : "v"(addr));
  return r;
}

__device__ __forceinline__ s16x8 cat8(s16x4 a, s16x4 b) {
  s16x8 r;
  r[0]=a[0]; r[1]=a[1]; r[2]=a[2]; r[3]=a[3];
  r[4]=b[0]; r[5]=b[1]; r[6]=b[2]; r[7]=b[3];
  return r;
}

// ---------------- small prep kernels ----------------

__global__ void k_cast(const float* __restrict__ src, unsigned short* __restrict__ dst, int n4) {
  int i = blockIdx.x * 256 + threadIdx.x;
  if (i >= n4) return;
  f32x4 v = ((const f32x4*)src)[i];
  u16x4 o;
  o[0] = f2bf(v[0]); o[1] = f2bf(v[1]); o[2] = f2bf(v[2]); o[3] = f2bf(v[3]);
  ((u16x4*)dst)[i] = o;
}

// column sums of hidden: two-stage, deterministic (no atomics -> top-k stable)
__global__ void k_rowsum_p(const float* __restrict__ x, float* __restrict__ part) {
  int d = blockIdx.x * 256 + threadIdx.x;
  int q0 = blockIdx.y * 128;
  float acc = 0.f;
  for (int q = q0; q < q0 + 128; ++q) acc += x[(size_t)q * HID + d];
  part[(size_t)blockIdx.y * HID + d] = acc;
}
__global__ void k_rowsum_r(const float* __restrict__ part, float* __restrict__ out) {
  int d = blockIdx.x * 256 + threadIdx.x;
  float acc = 0.f;
#pragma unroll
  for (int i = 0; i < 16; ++i) acc += part[(size_t)i * HID + d];
  out[d] = acc;
}

// out[n] = s * dot(vec, mat[n,:]) ; one wave per n, 4 waves/block
__global__ void k_dotrows(const float* __restrict__ vec, const float* __restrict__ mat,
                          float* __restrict__ out, int K, float s) {
  int n = blockIdx.x * 4 + (threadIdx.x >> 6);
  int lane = threadIdx.x & 63;
  const float* row = mat + (size_t)n * K;
  float acc = 0.f;
  for (int j = lane; j < K; j += 64) acc += vec[j] * row[j];
#pragma unroll
  for (int off = 32; off > 0; off >>= 1) acc += __shfl_down(acc, off, 64);
  if (lane == 0) out[n] = acc * s;
}

// stable top-k by rank counting (tie-break: lower index wins, matches lax.top_k)
__global__ void k_topk(const float* __restrict__ scores, int* __restrict__ idx) {
  __shared__ float s[KBLEN];
  int t = threadIdx.x;
  s[t] = scores[t];
  __syncthreads();
  float mine = s[t];
  int rank = 0;
  for (int j = 0; j < KBLEN; ++j) {
    float v = s[j];
    rank += (v > mine) || (v == mine && j < t);
  }
  if (rank < NTOPK) idx[rank] = t;
}

// cos/sin table
__global__ void k_cs(const int* __restrict__ pos_ids, float* __restrict__ cs) {
  int t = blockIdx.x * 256 + threadIdx.x;   // QLEN*64 threads
  int p = t >> 6, i = t & 63;
  float pos = (float)pos_ids[p];
  float invf = powf(10000.0f, -(float)i / 64.0f);
  float a = pos * invf;
  cs[p * 128 + i] = cosf(a);
  cs[p * 128 + 64 + i] = sinf(a);
}

// rope: raw fp32 [q][4096] -> bf16 head layout dst[h][RO+q][128]
__global__ void k_rope(const float* __restrict__ raw, const float* __restrict__ cs,
                       unsigned short* __restrict__ dst, int RH, int RO) {
  int t = blockIdx.x * 256 + threadIdx.x;   // QLEN*NH*64 threads
  int i = t & 63;
  int hh = (t >> 6) & 31;
  int q = t >> 11;
  float x1 = raw[(size_t)q * HID + hh * HD + i];
  float x2 = raw[(size_t)q * HID + hh * HD + 64 + i];
  float c = cs[q * 128 + i];
  float sn = cs[q * 128 + 64 + i];
  size_t base = ((size_t)hh * RH + RO + q) * HD;
  dst[base + i]      = f2bf(x1 * c - x2 * sn);
  dst[base + 64 + i] = f2bf(x2 * c + x1 * sn);
}

// gather selected KB rows into k_all[:, :128] / v_all[:, :128]
__global__ void k_gather(const float* __restrict__ kbk, const float* __restrict__ kbv,
                         const int* __restrict__ idx,
                         unsigned short* __restrict__ kall, unsigned short* __restrict__ vall) {
  int t = blockIdx.x * 256 + threadIdx.x;   // NH*NTOPK*HD threads
  int d = t & 127;
  int i = (t >> 7) & 127;
  int hh = t >> 14;
  int kr = idx[i];
  size_t src = (size_t)kr * HID + hh * HD + d;
  size_t dstoff = ((size_t)hh * KVLEN + i) * HD + d;
  kall[dstoff] = f2bf(kbk[src]);
  vall[dstoff] = f2bf(kbv[src]);
}

// ---------------- bf16 MFMA GEMM: C[m,n] = sum_k A[m,k]*B[n,k] ----------------
// 8-phase-style pipelined template (T1+T2+T3+T4+T5): BM=128, BN=256, BK=64,
// 512 threads = 8 waves (2M x 4N), per-wave 64x64 output. 3 LDS buffers
// (144 KiB) -> ONE raw s_barrier + ONE counted vmcnt(6) per K-tile; prefetch
// always 2 tiles ahead, never drained except the last tile. 16B-chunk XOR
// swizzle by row&7 (conflict-free b128 reads; same involution as attn K).
// MODE 0: fp32 row-major Cf[m*N+n]. MODE 1: bf16 head layout Cb[h][RO+m][d].
#define GBK 64
#define ABUF 8192    // elems per buffer for A (128x64)
#define BBUF 16384   // elems per buffer for B (256x64)
#define BUFE (ABUF + BBUF)

template<int MODE>
__global__ __launch_bounds__(512)
void gemm_bt(const unsigned short* __restrict__ A, const unsigned short* __restrict__ B,
             float* __restrict__ Cf, unsigned short* __restrict__ Cb,
             int M, int N, int K, int RH, int RO) {
  __shared__ unsigned short lds[3 * BUFE];   // 144 KiB
  const int tid = threadIdx.x;
  const int lane = tid & 63;
  const int wave = tid >> 6;
  const int lo = lane & 15, hi = lane >> 4;
  const int wm = wave >> 2, wn = wave & 3;

  // T1: bijective XCD swizzle (nwg % 8 == 0 by construction: 256 blocks)
  const int nwg = gridDim.x * gridDim.y;
  const int orig = blockIdx.y * gridDim.x + blockIdx.x;
  const int wg = (orig & 7) * (nwg >> 3) + (orig >> 3);
  const int bx = wg % gridDim.x, by = wg / gridDim.x;
  const int m0 = by * 128, n0 = bx * 256;

  auto stageA = [&](int kt, int bufe, int g) {
    int j0 = g * 512 + wave * 64;
    int j = j0 + lane;
    int row = j >> 3, cb = j & 7;
    gload_lds16(A + (size_t)(m0 + row) * K + kt * GBK + ((cb ^ (row & 7)) << 3),
                (void*)(lds + bufe + j0 * 8));
  };
  auto stageB = [&](int kt, int bufe, int g) {
    int j0 = g * 512 + wave * 64;
    int j = j0 + lane;
    int row = j >> 3, cb = j & 7;
    gload_lds16(B + (size_t)(n0 + row) * K + kt * GBK + ((cb ^ (row & 7)) << 3),
                (void*)(lds + bufe + ABUF + j0 * 8));
  };

  f32x4 acc[4][4] = {};

  // prologue: tiles 0 and 1 (12 loads in flight)
  stageA(0, 0, 0); stageA(0, 0, 1);
  stageB(0, 0, 0); stageB(0, 0, 1); stageB(0, 0, 2); stageB(0, 0, 3);
  stageA(1, BUFE, 0); stageA(1, BUFE, 1);
  stageB(1, BUFE, 0); stageB(1, BUFE, 1); stageB(1, BUFE, 2); stageB(1, BUFE, 3);

  const int NT = K / GBK;
  const int sa = (lo & 7) << 3;      // read-side swizzle (elems)
  int bi = 0;

  for (int kt = 0; kt < NT; ++kt) {
    // T4: counted drain — tile kt's 6 loads done, kt+1's stay in flight
    if (kt < NT - 1) { asm volatile("s_waitcnt vmcnt(6)" ::: "memory"); }
    else             { asm volatile("s_waitcnt vmcnt(0)" ::: "memory"); }
    __builtin_amdgcn_sched_barrier(0);
    __builtin_amdgcn_s_barrier();      // raw: no vmcnt(0) drain (T4)
    __builtin_amdgcn_sched_barrier(0);

    const int bufe = bi * BUFE;
    const int nbufe = ((bi + 2 >= 3) ? bi - 1 : bi + 2) * BUFE;
    const bool pre = (kt + 2 < NT);
    const unsigned short* Ab = lds + bufe;
    const unsigned short* Bb = lds + bufe + ABUF;
    const int arow = wm * 64 + lo;
    const int brow = wn * 64 + lo;

    s16x8 af[4], b01[2], b23[2];
    const int c0 = (hi * 8) ^ sa;          // kk=0 swizzled col
    const int c1 = (32 + hi * 8) ^ sa;     // kk=1 swizzled col

    // ---- phase 0: A(kk0) + B01(kk0) reads | stage A(kt+2) | MFMA j=0,1 kk0
#pragma unroll
    for (int i = 0; i < 4; ++i) af[i] = *(const s16x8*)(Ab + (arow + i * 16) * 64 + c0);
#pragma unroll
    for (int j = 0; j < 2; ++j) b01[j] = *(const s16x8*)(Bb + (brow + j * 16) * 64 + c0);
    if (pre) { stageA(kt + 2, nbufe, 0); stageA(kt + 2, nbufe, 1); }
    asm volatile("s_waitcnt lgkmcnt(0)" ::: "memory");
    __builtin_amdgcn_sched_barrier(0);
    __builtin_amdgcn_s_setprio(1);
#pragma unroll
    for (int i = 0; i < 4; ++i) {
      acc[i][0] = __builtin_amdgcn_mfma_f32_16x16x32_bf16(af[i], b01[0], acc[i][0], 0, 0, 0);
      acc[i][1] = __builtin_amdgcn_mfma_f32_16x16x32_bf16(af[i], b01[1], acc[i][1], 0, 0, 0);
    }
    __builtin_amdgcn_s_setprio(0);

    // ---- phase 1: B23(kk0) reads | stage B(kt+2) g0,g1 | MFMA j=2,3 kk0
#pragma unroll
    for (int j = 0; j < 2; ++j) b23[j] = *(const s16x8*)(Bb + (brow + (j + 2) * 16) * 64 + c0);
    if (pre) { stageB(kt + 2, nbufe, 0); stageB(kt + 2, nbufe, 1); }
    asm volatile("s_waitcnt lgkmcnt(0)" ::: "memory");
    __builtin_amdgcn_sched_barrier(0);
    __builtin_amdgcn_s_setprio(1);
#pragma unroll
    for (int i = 0; i < 4; ++i) {
      acc[i][2] = __builtin_amdgcn_mfma_f32_16x16x32_bf16(af[i], b23[0], acc[i][2], 0, 0, 0);
      acc[i][3] = __builtin_amdgcn_mfma_f32_16x16x32_bf16(af[i], b23[1], acc[i][3], 0, 0, 0);
    }
    __builtin_amdgcn_s_setprio(0);

    // ---- phase 2: A(kk1) + B01(kk1) reads | stage B(kt+2) g2,g3 | MFMA j=0,1 kk1
#pragma unroll
    for (int i = 0; i < 4; ++i) af[i] = *(const s16x8*)(Ab + (arow + i * 16) * 64 + c1);
#pragma unroll
    for (int j = 0; j < 2; ++j) b01[j] = *(const s16x8*)(Bb + (brow + j * 16) * 64 + c1);
    if (pre) { stageB(kt + 2, nbufe, 2); stageB(kt + 2, nbufe, 3); }
    asm volatile("s_waitcnt lgkmcnt(0)" ::: "memory");
    __builtin_amdgcn_sched_barrier(0);
    __builtin_amdgcn_s_setprio(1);
#pragma unroll
    for (int i = 0; i < 4; ++i) {
      acc[i][0] = __builtin_amdgcn_mfma_f32_16x16x32_bf16(af[i], b01[0], acc[i][0], 0, 0, 0);
      acc[i][1] = __builtin_amdgcn_mfma_f32_16x16x32_bf16(af[i], b01[1], acc[i][1], 0, 0, 0);
    }
    __builtin_amdgcn_s_setprio(0);

    // ---- phase 3: B23(kk1) reads | MFMA j=2,3 kk1
#pragma unroll
    for (int j = 0; j < 2; ++j) b23[j] = *(const s16x8*)(Bb + (brow + (j + 2) * 16) * 64 + c1);
    asm volatile("s_waitcnt lgkmcnt(0)" ::: "memory");
    __builtin_amdgcn_sched_barrier(0);
    __builtin_amdgcn_s_setprio(1);
#pragma unroll
    for (int i = 0; i < 4; ++i) {
      acc[i][2] = __builtin_amdgcn_mfma_f32_16x16x32_bf16(af[i], b23[0], acc[i][2], 0, 0, 0);
      acc[i][3] = __builtin_amdgcn_mfma_f32_16x16x32_bf16(af[i], b23[1], acc[i][3], 0, 0, 0);
    }
    __builtin_amdgcn_s_setprio(0);

    bi = (bi + 1 == 3) ? 0 : bi + 1;
  }

  // epilogue
#pragma unroll
  for (int i = 0; i < 4; ++i) {
#pragma unroll
    for (int j = 0; j < 4; ++j) {
#pragma unroll
      for (int r = 0; r < 4; ++r) {
        int row = m0 + wm * 64 + i * 16 + hi * 4 + r;   // C/D: row=(l>>4)*4+reg
        int col = n0 + wn * 64 + j * 16 + lo;           //      col=l&15  [m89]
        float v = acc[i][j][r];
        if (MODE == 0) {
          Cf[(size_t)row * N + col] = v;
        } else {
          int hh = col >> 7, d = col & 127;
          Cb[((size_t)hh * RH + RO + row) * HD + d] = f2bf(v);
        }
      }
    }
  }
}

// ---------------- flash attention (unchanged from R2) ----------------
__global__ __launch_bounds__(256)
void attn_kernel(const unsigned short* __restrict__ qh,
                 const unsigned short* __restrict__ kall,
                 const unsigned short* __restrict__ vall,
                 const float* __restrict__ sshift,
                 unsigned short* __restrict__ ctx) {
  __shared__ __align__(1024) unsigned short Ks[64 * 128];
  __shared__ __align__(1024) unsigned short Vs[64 * 128];
  __shared__ __align__(16)  unsigned short Plds[4][16 * 72];

  int orig = blockIdx.y * 16 + blockIdx.x;
  int wgid = (orig & 7) * 64 + (orig >> 3);
  int h = wgid >> 4;
  int xch = wgid & 15;

  const int tid = threadIdx.x;
  const int lane = tid & 63;
  const int wave = tid >> 6;
  const int lo = lane & 15;
  const int hi = lane >> 4;
  const float shift = sshift[h];

  const unsigned short* kb = kall + (size_t)h * KVLEN * HD;
  const unsigned short* vb = vall + (size_t)h * KVLEN * HD;

  const unsigned vsb = (unsigned)(uintptr_t)(&Vs[0]);

#pragma unroll 1
  for (int half = 0; half < 2; ++half) {
    const int qc = half ? (31 - xch) : xch;
    const int m0 = qc * 64;

    s16x8 qf[4];
    {
      const unsigned short* qp = qh + ((size_t)h * QLEN + m0 + wave * 16 + lo) * HD + hi * 8;
#pragma unroll
      for (int kc = 0; kc < 4; ++kc) qf[kc] = *(const s16x8*)(qp + kc * 32);
    }

    float m_run[4], l_run[4];
#pragma unroll
    for (int r = 0; r < 4; ++r) { m_run[r] = -1e30f; l_run[r] = 0.f; }
    f32x4 o[8] = {};

    const int nt = qc + 3;
    const int qrow = m0 + wave * 16 + hi * 4;

    for (int kt = 0; kt < nt; ++kt) {
      const unsigned short* kg = kb + (size_t)kt * 64 * HD;
      const unsigned short* vg = vb + (size_t)kt * 64 * HD;
      __syncthreads();
#pragma unroll
      for (int it = 0; it < 4; ++it) {
        int j0 = it * 256 + wave * 64;
        int j = j0 + lane;
        int row = j >> 4, cb = j & 15;
        gload_lds16(kg + row * 128 + ((cb ^ (row & 7)) * 8), (void*)(Ks + j0 * 8));
        int kq = j >> 6, dc = (j >> 3) & 7, kr = (j >> 1) & 3, hf = j & 1;
        gload_lds16(vg + (kq * 4 + kr) * 128 + dc * 16 + hf * 8, (void*)(Vs + j0 * 8));
      }
      __syncthreads();

      f32x4 s[4] = {};
#pragma unroll
      for (int kc = 0; kc < 4; ++kc) {
#pragma unroll
        for (int g = 0; g < 4; ++g) {
          int key = g * 16 + lo;
          s16x8 kf = *(const s16x8*)(Ks + key * 128 + (((kc * 4 + hi) ^ (key & 7)) * 8));
          s[g] = __builtin_amdgcn_mfma_f32_16x16x32_bf16(qf[kc], kf, s[g], 0, 0, 0);
        }
      }

      const int kvbase = kt * 64;
      float sv[4][4], mx[4];
#pragma unroll
      for (int r = 0; r < 4; ++r) {
        int qr = qrow + r;
#pragma unroll
        for (int g = 0; g < 4; ++g) {
          int kv = kvbase + g * 16 + lo;
          float v = s[g][r] * SCALE;
          v = (kv < NTOPK) ? (v + shift) : ((kv - NTOPK > qr) ? PADV : v);
          sv[g][r] = v;
        }
        mx[r] = fmaxf(fmaxf(sv[0][r], sv[1][r]), fmaxf(sv[2][r], sv[3][r]));
      }
#pragma unroll
      for (int off = 1; off < 16; off <<= 1)
#pragma unroll
        for (int r = 0; r < 4; ++r) mx[r] = fmaxf(mx[r], __shfl_xor(mx[r], off, 64));

      float alpha[4], rs[4];
#pragma unroll
      for (int r = 0; r < 4; ++r) {
        float mn = fmaxf(m_run[r], mx[r]);
        alpha[r] = __expf(m_run[r] - mn);
        m_run[r] = mn;
        float acc = 0.f;
#pragma unroll
        for (int g = 0; g < 4; ++g) {
          float p = __expf(sv[g][r] - mn);
          acc += p;
          Plds[wave][(hi * 4 + r) * 72 + g * 16 + lo] = f2bf(p);
        }
        rs[r] = acc;
      }
#pragma unroll
      for (int off = 1; off < 16; off <<= 1)
#pragma unroll
        for (int r = 0; r < 4; ++r) rs[r] += __shfl_xor(rs[r], off, 64);
#pragma unroll
      for (int r = 0; r < 4; ++r) l_run[r] = l_run[r] * alpha[r] + rs[r];
#pragma unroll
      for (int db = 0; db < 8; ++db)
#pragma unroll
        for (int r = 0; r < 4; ++r) o[db][r] *= alpha[r];

      s16x8 pf0 = *(const s16x8*)(&Plds[wave][lo * 72 + hi * 8]);
      s16x8 pf1 = *(const s16x8*)(&Plds[wave][lo * 72 + 32 + hi * 8]);
      const unsigned vb0 = vsb + hi * 2048 + lo * 8;
#pragma unroll
      for (int dbp = 0; dbp < 4; ++dbp) {
        s16x4 t[2][2][2];
#pragma unroll
        for (int dbi = 0; dbi < 2; ++dbi) {
          unsigned a0 = vb0 + (dbp * 2 + dbi) * 128;
          t[dbi][0][0] = tr16(a0);
          t[dbi][0][1] = tr16(a0 + 1024);
          t[dbi][1][0] = tr16(a0 + 8192);
          t[dbi][1][1] = tr16(a0 + 8192 + 1024);
        }
        asm volatile("s_waitcnt lgkmcnt(0)" ::: "memory");
        __builtin_amdgcn_sched_barrier(0);
#pragma unroll
        for (int dbi = 0; dbi < 2; ++dbi) {
          int db = dbp * 2 + dbi;
          o[db] = __builtin_amdgcn_mfma_f32_16x16x32_bf16(pf0, cat8(t[dbi][0][0], t[dbi][0][1]), o[db], 0, 0, 0);
          o[db] = __builtin_amdgcn_mfma_f32_16x16x32_bf16(pf1, cat8(t[dbi][1][0], t[dbi][1][1]), o[db], 0, 0, 0);
        }
      }
    } // kt

#pragma unroll
    for (int db = 0; db < 8; ++db) {
#pragma unroll
      for (int r = 0; r < 4; ++r) {
        int row = qrow + r;
        int col = h * HD + db * 16 + lo;
        ctx[(size_t)row * HID + col] = f2bf(o[db][r] / l_run[r]);
      }
    }
  } // half
}

// ---------------- launch ----------------

extern "C" void kernel_launch(void* const* d_in, const int* in_sizes, int n_in,
                              void* d_out, int out_size, void* d_ws, size_t ws_size,
                              hipStream_t stream) {
  const float* hidden    = (const float*)d_in[0];
  const int*   pos       = (const int*)d_in[2];
  const float* kb_keys   = (const float*)d_in[3];
  const float* kb_values = (const float*)d_in[4];
  const float* Wq        = (const float*)d_in[5];
  const float* Wq2       = (const float*)d_in[6];
  const float* Wk        = (const float*)d_in[7];
  const float* Wv        = (const float*)d_in[8];
  const float* Wo        = (const float*)d_in[9];
  const float* sshift    = (const float*)d_in[10];
  float* out = (float*)d_out;

  char* ws = (char*)d_ws;
  size_t off = 0;
  auto alloc = [&](size_t bytes) { char* p = ws + off; off += (bytes + 255) & ~(size_t)255; return p; };
  unsigned short* hidden_bf = (unsigned short*)alloc((size_t)QLEN * HID * 2);
  unsigned short* wbuf      = (unsigned short*)alloc((size_t)HID * HID * 2);
  float*          qraw      = (float*)alloc((size_t)QLEN * HID * 4);
  float*          kraw      = (float*)alloc((size_t)QLEN * HID * 4);
  unsigned short* qbf       = (unsigned short*)alloc((size_t)NH * QLEN * HD * 2);
  unsigned short* kallp     = (unsigned short*)alloc((size_t)NH * KVLEN * HD * 2);
  unsigned short* vallp     = (unsigned short*)alloc((size_t)NH * KVLEN * HD * 2);
  unsigned short* ctx       = (unsigned short*)alloc((size_t)QLEN * HID * 2);
  float*          cs        = (float*)alloc((size_t)QLEN * 128 * 4);
  float*          part      = (float*)alloc((size_t)16 * HID * 4);
  float*          hsum      = (float*)alloc(HID * 4);
  float*          qs        = (float*)alloc(HID * 4);
  float*          scores    = (float*)alloc(KBLEN * 4);
  int*            idx       = (int*)alloc(NTOPK * 4);

  dim3 blk(256);

  k_cast<<<QLEN * HID / 4 / 256, blk, 0, stream>>>(hidden, hidden_bf, QLEN * HID / 4);
  k_rowsum_p<<<dim3(HID / 256, 16), blk, 0, stream>>>(hidden, part);
  k_rowsum_r<<<HID / 256, blk, 0, stream>>>(part, hsum);
  k_dotrows<<<HID / 4, blk, 0, stream>>>(hsum, Wq2, qs, HID, 1.0f);
  k_dotrows<<<KBLEN / 4, blk, 0, stream>>>(qs, kb_keys, scores, HID, SCALE);
  k_topk<<<1, KBLEN, 0, stream>>>(scores, idx);
  k_cs<<<QLEN * 64 / 256, blk, 0, stream>>>(pos, cs);

  dim3 ggrid(HID / 256, QLEN / 128);  // (16, 16) = 256 blocks, 1/CU
  dim3 gblk(512);
  int wcast_blocks = HID * HID / 4 / 256;

  // Q projection -> qraw (fp32)
  k_cast<<<wcast_blocks, blk, 0, stream>>>(Wq, wbuf, HID * HID / 4);
  gemm_bt<0><<<ggrid, gblk, 0, stream>>>(hidden_bf, wbuf, qraw, nullptr, QLEN, HID, HID, 0, 0);
  // K projection -> kraw (fp32)
  k_cast<<<wcast_blocks, blk, 0, stream>>>(Wk, wbuf, HID * HID / 4);
  gemm_bt<0><<<ggrid, gblk, 0, stream>>>(hidden_bf, wbuf, kraw, nullptr, QLEN, HID, HID, 0, 0);
  // V projection -> v_all[h][128+q][d] (bf16)
  k_cast<<<wcast_blocks, blk, 0, stream>>>(Wv, wbuf, HID * HID / 4);
  gemm_bt<1><<<ggrid, gblk, 0, stream>>>(hidden_bf, wbuf, nullptr, vallp, QLEN, HID, HID, KVLEN, NTOPK);

  // rope -> head layouts
  k_rope<<<QLEN * NH * 64 / 256, blk, 0, stream>>>(qraw, cs, qbf, QLEN, 0);
  k_rope<<<QLEN * NH * 64 / 256, blk, 0, stream>>>(kraw, cs, kallp, KVLEN, NTOPK);

  // gather selected KB keys/values into k_all/v_all[:, :128]
  k_gather<<<NH * NTOPK * HD / 256, blk, 0, stream>>>(kb_keys, kb_values, idx, kallp, vallp);

  // flash attention -> ctx bf16 [q][h*128+d]
  dim3 agrid(16, NH);
  attn_kernel<<<agrid, blk, 0, stream>>>(qbf, kallp, vallp, sshift, ctx);

  // output projection -> d_out fp32
  k_cast<<<wcast_blocks, blk, 0, stream>>>(Wo, wbuf, HID * HID / 4);
  gemm_bt<0><<<ggrid, gblk, 0, stream>>>(ctx, wbuf, out, nullptr, QLEN, HID, HID, 0, 0);
}

// Round 4
// 577.181 us; speedup vs baseline: 1.5913x; 1.0320x over previous
//
#include <hip/hip_runtime.h>
#include <stdint.h>
#include <stddef.h>

#define NH 32
#define HD 128
#define HID 4096
#define QLEN 2048
#define KBLEN 1024
#define NTOPK 128
#define KVLEN 2176   // NTOPK + QLEN
#define PADV -1e9f
#define SCALE 0.08838834764831845f
#define LOG2E 1.4426950408889634f
#define SC2 (SCALE * LOG2E)          // score scale in log2 domain
#define DEFER_THR 8.0f

typedef __attribute__((ext_vector_type(4))) float f32x4;
typedef __attribute__((ext_vector_type(4))) unsigned short u16x4;
typedef __attribute__((ext_vector_type(8))) short s16x8;
typedef __attribute__((ext_vector_type(4))) short s16x4;

typedef const __attribute__((address_space(1))) void* gas1_t;
typedef __attribute__((address_space(3))) void* las3_t;

__device__ __forceinline__ void gload_lds16(const void* g, void* l) {
  __builtin_amdgcn_global_load_lds((gas1_t)g, (las3_t)l, 16, 0, 0);
}

__device__ __forceinline__ unsigned short f2bf(float x) {
  union { float f; unsigned u; } z; z.f = x;
  unsigned r = z.u + 0x7fffu + ((z.u >> 16) & 1u);
  return (unsigned short)(r >> 16);
}

// hardware transpose read [m156/m162 model]
__device__ __forceinline__ s16x4 tr16(unsigned addr) {
  s16x4 r;
  asm volatile("ds_read_b64_tr_b16 %0, %1" : "=v"(r) : "v"(addr));
  return r;
}

__device__ __forceinline__ s16x8 cat8(s16x4 a, s16x4 b) {
  s16x8 r;
  r[0]=a[0]; r[1]=a[1]; r[2]=a[2]; r[3]=a[3];
  r[4]=b[0]; r[5]=b[1]; r[6]=b[2]; r[7]=b[3];
  return r;
}

// ---------------- small prep kernels ----------------

__global__ void k_cast(const float* __restrict__ src, unsigned short* __restrict__ dst, int n4) {
  int i = blockIdx.x * 256 + threadIdx.x;
  if (i >= n4) return;
  f32x4 v = ((const f32x4*)src)[i];
  u16x4 o;
  o[0] = f2bf(v[0]); o[1] = f2bf(v[1]); o[2] = f2bf(v[2]); o[3] = f2bf(v[3]);
  ((u16x4*)dst)[i] = o;
}

// column sums of hidden: two-stage, deterministic (no atomics -> top-k stable)
__global__ void k_rowsum_p(const float* __restrict__ x, float* __restrict__ part) {
  int d = blockIdx.x * 256 + threadIdx.x;
  int q0 = blockIdx.y * 128;
  float acc = 0.f;
  for (int q = q0; q < q0 + 128; ++q) acc += x[(size_t)q * HID + d];
  part[(size_t)blockIdx.y * HID + d] = acc;
}
__global__ void k_rowsum_r(const float* __restrict__ part, float* __restrict__ out) {
  int d = blockIdx.x * 256 + threadIdx.x;
  float acc = 0.f;
#pragma unroll
  for (int i = 0; i < 16; ++i) acc += part[(size_t)i * HID + d];
  out[d] = acc;
}

// out[n] = s * dot(vec, mat[n,:]) ; one wave per n, 4 waves/block
__global__ void k_dotrows(const float* __restrict__ vec, const float* __restrict__ mat,
                          float* __restrict__ out, int K, float s) {
  int n = blockIdx.x * 4 + (threadIdx.x >> 6);
  int lane = threadIdx.x & 63;
  const float* row = mat + (size_t)n * K;
  float acc = 0.f;
  for (int j = lane; j < K; j += 64) acc += vec[j] * row[j];
#pragma unroll
  for (int off = 32; off > 0; off >>= 1) acc += __shfl_down(acc, off, 64);
  if (lane == 0) out[n] = acc * s;
}

// stable top-k by rank counting (tie-break: lower index wins, matches lax.top_k)
__global__ void k_topk(const float* __restrict__ scores, int* __restrict__ idx) {
  __shared__ float s[KBLEN];
  int t = threadIdx.x;
  s[t] = scores[t];
  __syncthreads();
  float mine = s[t];
  int rank = 0;
  for (int j = 0; j < KBLEN; ++j) {
    float v = s[j];
    rank += (v > mine) || (v == mine && j < t);
  }
  if (rank < NTOPK) idx[rank] = t;
}

// cos/sin table, interleaved pairs: cs[p*64+i] = {cos, sin} of pos_p * invf_i
__global__ void k_cs(const int* __restrict__ pos_ids, float2* __restrict__ cs) {
  int t = blockIdx.x * 256 + threadIdx.x;   // QLEN*64 threads
  int p = t >> 6, i = t & 63;
  float pos = (float)pos_ids[p];
  float invf = powf(10000.0f, -(float)i / 64.0f);
  float a = pos * invf;
  cs[p * 64 + i] = make_float2(cosf(a), sinf(a));
}

// gather selected KB rows into k_all[:, :128] / v_all[:, :128]
__global__ void k_gather(const float* __restrict__ kbk, const float* __restrict__ kbv,
                         const int* __restrict__ idx,
                         unsigned short* __restrict__ kall, unsigned short* __restrict__ vall) {
  int t = blockIdx.x * 256 + threadIdx.x;   // NH*NTOPK*HD threads
  int d = t & 127;
  int i = (t >> 7) & 127;
  int hh = t >> 14;
  int kr = idx[i];
  size_t src = (size_t)kr * HID + hh * HD + d;
  size_t dstoff = ((size_t)hh * KVLEN + i) * HD + d;
  kall[dstoff] = f2bf(kbk[src]);
  vall[dstoff] = f2bf(kbv[src]);
}

// ---------------- bf16 MFMA GEMM: C[m,n] = sum_k A[m,k]*B[n,k] ----------------
// Pipelined template (T1+T2+T3+T4+T5): BM=128, BN=256, BK=64, 512 threads =
// 8 waves (2M x 4N), per-wave 64x64 output. 3 LDS buffers, ONE raw s_barrier
// + ONE counted vmcnt(6) per K-tile. Wave's 4 column groups remapped to
// {d, d+16, d+64, d+80} within one head so rotate-half pairs are register-
// local (acc[i][j] ~ acc[i][j+2]).
// MODE 0: fp32 row-major Cf. MODE 1: bf16 head layout Cb[h][RO+m][d].
// MODE 2: RoPE-fused bf16 head layout (rotate-half with cs2 table).
#define GBK 64
#define ABUF 8192    // elems per buffer for A (128x64)
#define BBUF 16384   // elems per buffer for B (256x64)
#define BUFE (ABUF + BBUF)

template<int MODE>
__global__ __launch_bounds__(512)
void gemm_bt(const unsigned short* __restrict__ A, const unsigned short* __restrict__ B,
             float* __restrict__ Cf, unsigned short* __restrict__ Cb,
             int M, int N, int K, int RH, int RO, const float2* __restrict__ cs2) {
  __shared__ unsigned short lds[3 * BUFE];   // 144 KiB
  const int tid = threadIdx.x;
  const int lane = tid & 63;
  const int wave = tid >> 6;
  const int lo = lane & 15, hi = lane >> 4;
  const int wm = wave >> 2, wn = wave & 3;

  // T1: bijective XCD swizzle (nwg % 8 == 0 by construction: 256 blocks)
  const int nwg = gridDim.x * gridDim.y;
  const int orig = blockIdx.y * gridDim.x + blockIdx.x;
  const int wg = (orig & 7) * (nwg >> 3) + (orig >> 3);
  const int bx = wg % gridDim.x, by = wg / gridDim.x;
  const int m0 = by * 128, n0 = bx * 256;

  auto stageA = [&](int kt, int bufe, int g) {
    int j0 = g * 512 + wave * 64;
    int j = j0 + lane;
    int row = j >> 3, cb = j & 7;
    gload_lds16(A + (size_t)(m0 + row) * K + kt * GBK + ((cb ^ (row & 7)) << 3),
                (void*)(lds + bufe + j0 * 8));
  };
  auto stageB = [&](int kt, int bufe, int g) {
    int j0 = g * 512 + wave * 64;
    int j = j0 + lane;
    int row = j >> 3, cb = j & 7;
    gload_lds16(B + (size_t)(n0 + row) * K + kt * GBK + ((cb ^ (row & 7)) << 3),
                (void*)(lds + bufe + ABUF + j0 * 8));
  };

  f32x4 acc[4][4] = {};

  // prologue: tiles 0 and 1 (12 loads in flight)
  stageA(0, 0, 0); stageA(0, 0, 1);
  stageB(0, 0, 0); stageB(0, 0, 1); stageB(0, 0, 2); stageB(0, 0, 3);
  stageA(1, BUFE, 0); stageA(1, BUFE, 1);
  stageB(1, BUFE, 0); stageB(1, BUFE, 1); stageB(1, BUFE, 2); stageB(1, BUFE, 3);

  const int NT = K / GBK;
  const int sa = (lo & 7) << 3;      // read-side swizzle (elems)
  // column-group base: head-pair-local mapping {0,16,64,80}
  const int bbase = (wn >> 1) * 128 + (wn & 1) * 32;
  int bi = 0;

  for (int kt = 0; kt < NT; ++kt) {
    if (kt < NT - 1) { asm volatile("s_waitcnt vmcnt(6)" ::: "memory"); }
    else             { asm volatile("s_waitcnt vmcnt(0)" ::: "memory"); }
    __builtin_amdgcn_sched_barrier(0);
    __builtin_amdgcn_s_barrier();      // raw: no vmcnt(0) drain (T4)
    __builtin_amdgcn_sched_barrier(0);

    const int bufe = bi * BUFE;
    const int nbufe = ((bi + 2 >= 3) ? bi - 1 : bi + 2) * BUFE;
    const bool pre = (kt + 2 < NT);
    const unsigned short* Ab = lds + bufe;
    const unsigned short* Bb = lds + bufe + ABUF;
    const int arow = wm * 64 + lo;
    const int brow = bbase + lo;

    s16x8 af[4], b01[2], b23[2];
    const int c0 = (hi * 8) ^ sa;          // kk=0 swizzled col
    const int c1 = (32 + hi * 8) ^ sa;     // kk=1 swizzled col

    // ---- phase 0: A(kk0) + B01(kk0) reads | stage A(kt+2) | MFMA j=0,1 kk0
#pragma unroll
    for (int i = 0; i < 4; ++i) af[i] = *(const s16x8*)(Ab + (arow + i * 16) * 64 + c0);
    b01[0] = *(const s16x8*)(Bb + (brow +  0) * 64 + c0);
    b01[1] = *(const s16x8*)(Bb + (brow + 16) * 64 + c0);
    if (pre) { stageA(kt + 2, nbufe, 0); stageA(kt + 2, nbufe, 1); }
    asm volatile("s_waitcnt lgkmcnt(0)" ::: "memory");
    __builtin_amdgcn_sched_barrier(0);
    __builtin_amdgcn_s_setprio(1);
#pragma unroll
    for (int i = 0; i < 4; ++i) {
      acc[i][0] = __builtin_amdgcn_mfma_f32_16x16x32_bf16(af[i], b01[0], acc[i][0], 0, 0, 0);
      acc[i][1] = __builtin_amdgcn_mfma_f32_16x16x32_bf16(af[i], b01[1], acc[i][1], 0, 0, 0);
    }
    __builtin_amdgcn_s_setprio(0);

    // ---- phase 1: B23(kk0) reads | stage B(kt+2) g0,g1 | MFMA j=2,3 kk0
    b23[0] = *(const s16x8*)(Bb + (brow + 64) * 64 + c0);
    b23[1] = *(const s16x8*)(Bb + (brow + 80) * 64 + c0);
    if (pre) { stageB(kt + 2, nbufe, 0); stageB(kt + 2, nbufe, 1); }
    asm volatile("s_waitcnt lgkmcnt(0)" ::: "memory");
    __builtin_amdgcn_sched_barrier(0);
    __builtin_amdgcn_s_setprio(1);
#pragma unroll
    for (int i = 0; i < 4; ++i) {
      acc[i][2] = __builtin_amdgcn_mfma_f32_16x16x32_bf16(af[i], b23[0], acc[i][2], 0, 0, 0);
      acc[i][3] = __builtin_amdgcn_mfma_f32_16x16x32_bf16(af[i], b23[1], acc[i][3], 0, 0, 0);
    }
    __builtin_amdgcn_s_setprio(0);

    // ---- phase 2: A(kk1) + B01(kk1) reads | stage B(kt+2) g2,g3 | MFMA j=0,1 kk1
#pragma unroll
    for (int i = 0; i < 4; ++i) af[i] = *(const s16x8*)(Ab + (arow + i * 16) * 64 + c1);
    b01[0] = *(const s16x8*)(Bb + (brow +  0) * 64 + c1);
    b01[1] = *(const s16x8*)(Bb + (brow + 16) * 64 + c1);
    if (pre) { stageB(kt + 2, nbufe, 2); stageB(kt + 2, nbufe, 3); }
    asm volatile("s_waitcnt lgkmcnt(0)" ::: "memory");
    __builtin_amdgcn_sched_barrier(0);
    __builtin_amdgcn_s_setprio(1);
#pragma unroll
    for (int i = 0; i < 4; ++i) {
      acc[i][0] = __builtin_amdgcn_mfma_f32_16x16x32_bf16(af[i], b01[0], acc[i][0], 0, 0, 0);
      acc[i][1] = __builtin_amdgcn_mfma_f32_16x16x32_bf16(af[i], b01[1], acc[i][1], 0, 0, 0);
    }
    __builtin_amdgcn_s_setprio(0);

    // ---- phase 3: B23(kk1) reads | MFMA j=2,3 kk1
    b23[0] = *(const s16x8*)(Bb + (brow + 64) * 64 + c1);
    b23[1] = *(const s16x8*)(Bb + (brow + 80) * 64 + c1);
    asm volatile("s_waitcnt lgkmcnt(0)" ::: "memory");
    __builtin_amdgcn_sched_barrier(0);
    __builtin_amdgcn_s_setprio(1);
#pragma unroll
    for (int i = 0; i < 4; ++i) {
      acc[i][2] = __builtin_amdgcn_mfma_f32_16x16x32_bf16(af[i], b23[0], acc[i][2], 0, 0, 0);
      acc[i][3] = __builtin_amdgcn_mfma_f32_16x16x32_bf16(af[i], b23[1], acc[i][3], 0, 0, 0);
    }
    __builtin_amdgcn_s_setprio(0);

    bi = (bi + 1 == 3) ? 0 : bi + 1;
  }

  // epilogue: col = n0 + bbase + (j>>1)*64 + (j&1)*16 + lo   [remapped groups]
  if (MODE == 2) {
    // RoPE: pair (acc[i][j], acc[i][j+2]) = (x[d], x[d+64]), d < 64
#pragma unroll
    for (int i = 0; i < 4; ++i) {
#pragma unroll
      for (int j = 0; j < 2; ++j) {
#pragma unroll
        for (int r = 0; r < 4; ++r) {
          int row = m0 + wm * 64 + i * 16 + hi * 4 + r;
          int col = n0 + bbase + j * 16 + lo;
          int hh = col >> 7, d = col & 127;          // d in [0,64)
          float2 cp = cs2[row * 64 + d];
          float x1 = acc[i][j][r], x2 = acc[i][j + 2][r];
          size_t base = ((size_t)hh * RH + RO + row) * HD;
          Cb[base + d]      = f2bf(x1 * cp.x - x2 * cp.y);
          Cb[base + d + 64] = f2bf(x2 * cp.x + x1 * cp.y);
        }
      }
    }
  } else {
#pragma unroll
    for (int i = 0; i < 4; ++i) {
#pragma unroll
      for (int j = 0; j < 4; ++j) {
#pragma unroll
        for (int r = 0; r < 4; ++r) {
          int row = m0 + wm * 64 + i * 16 + hi * 4 + r;   // C/D: row=(l>>4)*4+reg
          int col = n0 + bbase + (j >> 1) * 64 + (j & 1) * 16 + lo;
          float v = acc[i][j][r];
          if (MODE == 0) {
            Cf[(size_t)row * N + col] = v;
          } else {
            int hh = col >> 7, d = col & 127;
            Cb[((size_t)hh * RH + RO + row) * HD + d] = f2bf(v);
          }
        }
      }
    }
  }
}

// ---------------- flash attention ----------------
// Block = (head, paired q-chunks {x, 31-x}) -> exactly 37 KV-tiles per block.
// 4 waves x 16 q-rows, KVBLK=64. Double-buffered K/V staging (T3 minimum
// 2-phase: STAGE(t+1) issued before compute(t), one barrier per tile).
// Softmax in log2 domain with defer-max (T13, THR=8, wave-uniform branch).
__global__ __launch_bounds__(256)
void attn_kernel(const unsigned short* __restrict__ qh,
                 const unsigned short* __restrict__ kall,
                 const unsigned short* __restrict__ vall,
                 const float* __restrict__ sshift,
                 unsigned short* __restrict__ ctx) {
  __shared__ __align__(1024) unsigned short Ks[2][64 * 128];
  __shared__ __align__(1024) unsigned short Vs[2][64 * 128];
  __shared__ __align__(16)  unsigned short Plds[4][16 * 72];

  int orig = blockIdx.y * 16 + blockIdx.x;
  int wgid = (orig & 7) * 64 + (orig >> 3);
  int h = wgid >> 4;
  int xch = wgid & 15;

  const int tid = threadIdx.x;
  const int lane = tid & 63;
  const int wave = tid >> 6;
  const int lo = lane & 15;
  const int hi = lane >> 4;
  const float shiftL = sshift[h] * LOG2E;

  const unsigned short* kb = kall + (size_t)h * KVLEN * HD;
  const unsigned short* vb = vall + (size_t)h * KVLEN * HD;

#pragma unroll 1
  for (int half = 0; half < 2; ++half) {
    const int qc = half ? (31 - xch) : xch;
    const int m0 = qc * 64;

    s16x8 qf[4];
    {
      const unsigned short* qp = qh + ((size_t)h * QLEN + m0 + wave * 16 + lo) * HD + hi * 8;
#pragma unroll
      for (int kc = 0; kc < 4; ++kc) qf[kc] = *(const s16x8*)(qp + kc * 32);
    }

    float m_run[4], l_run[4];
#pragma unroll
    for (int r = 0; r < 4; ++r) { m_run[r] = -1e30f; l_run[r] = 0.f; }
    f32x4 o[8] = {};

    const int nt = qc + 3;
    const int qrow = m0 + wave * 16 + hi * 4;
    int buf = 0;

    // stage tile kt into buffer b
    auto STAGE = [&](int kt, int b) {
      const unsigned short* kg = kb + (size_t)kt * 64 * HD;
      const unsigned short* vg = vb + (size_t)kt * 64 * HD;
#pragma unroll
      for (int it = 0; it < 4; ++it) {
        int j0 = it * 256 + wave * 64;
        int j = j0 + lane;
        int row = j >> 4, cb = j & 15;
        gload_lds16(kg + row * 128 + ((cb ^ (row & 7)) * 8), (void*)(Ks[b] + j0 * 8));
        int kq = j >> 6, dc = (j >> 3) & 7, kr = (j >> 1) & 3, hf = j & 1;
        gload_lds16(vg + (kq * 4 + kr) * 128 + dc * 16 + hf * 8, (void*)(Vs[b] + j0 * 8));
      }
    };

    STAGE(0, 0);
    __syncthreads();   // implicit vmcnt(0): tile 0 staged

    for (int kt = 0; kt < nt; ++kt) {
      if (kt + 1 < nt) STAGE(kt + 1, buf ^ 1);

      // S = Q K^T : 16 q-rows x 64 keys per wave
      f32x4 s[4] = {};
#pragma unroll
      for (int kc = 0; kc < 4; ++kc) {
#pragma unroll
        for (int g = 0; g < 4; ++g) {
          int key = g * 16 + lo;
          s16x8 kf = *(const s16x8*)(Ks[buf] + key * 128 + (((kc * 4 + hi) ^ (key & 7)) * 8));
          s[g] = __builtin_amdgcn_mfma_f32_16x16x32_bf16(qf[kc], kf, s[g], 0, 0, 0);
        }
      }

      // mask + log2-domain online softmax
      const int kvbase = kt * 64;
      float sv[4][4], mx[4];
#pragma unroll
      for (int r = 0; r < 4; ++r) {
        int qr = qrow + r;
#pragma unroll
        for (int g = 0; g < 4; ++g) {
          int kv = kvbase + g * 16 + lo;
          float v = s[g][r] * SC2;
          v = (kv < NTOPK) ? (v + shiftL) : ((kv - NTOPK > qr) ? PADV : v);
          sv[g][r] = v;
        }
        mx[r] = fmaxf(fmaxf(sv[0][r], sv[1][r]), fmaxf(sv[2][r], sv[3][r]));
      }
#pragma unroll
      for (int off = 1; off < 16; off <<= 1)
#pragma unroll
        for (int r = 0; r < 4; ++r) mx[r] = fmaxf(mx[r], __shfl_xor(mx[r], off, 64));

      // T13 defer-max: mx/m_run wave-uniform -> uniform branch
      bool need = false;
#pragma unroll
      for (int r = 0; r < 4; ++r) need = need || (mx[r] > m_run[r] + DEFER_THR);
      if (need) {
#pragma unroll
        for (int r = 0; r < 4; ++r) {
          float mn = fmaxf(m_run[r], mx[r]);
          float alpha = __builtin_amdgcn_exp2f(m_run[r] - mn);
          m_run[r] = mn;
          l_run[r] *= alpha;
#pragma unroll
          for (int db = 0; db < 8; ++db) o[db][r] *= alpha;
        }
      }

      float rs[4];
#pragma unroll
      for (int r = 0; r < 4; ++r) {
        float acc = 0.f;
#pragma unroll
        for (int g = 0; g < 4; ++g) {
          float p = __builtin_amdgcn_exp2f(sv[g][r] - m_run[r]);
          acc += p;
          Plds[wave][(hi * 4 + r) * 72 + g * 16 + lo] = f2bf(p);
        }
        rs[r] = acc;
      }
#pragma unroll
      for (int off = 1; off < 16; off <<= 1)
#pragma unroll
        for (int r = 0; r < 4; ++r) rs[r] += __shfl_xor(rs[r], off, 64);
#pragma unroll
      for (int r = 0; r < 4; ++r) l_run[r] += rs[r];

      // PV: A = P (same-wave LDS round trip), B = V^T via tr16
      s16x8 pf0 = *(const s16x8*)(&Plds[wave][lo * 72 + hi * 8]);
      s16x8 pf1 = *(const s16x8*)(&Plds[wave][lo * 72 + 32 + hi * 8]);
      const unsigned vb0 = (unsigned)(uintptr_t)(&Vs[buf][0]) + hi * 2048 + lo * 8;
#pragma unroll
      for (int dbp = 0; dbp < 4; ++dbp) {
        s16x4 t[2][2][2];
#pragma unroll
        for (int dbi = 0; dbi < 2; ++dbi) {
          unsigned a0 = vb0 + (dbp * 2 + dbi) * 128;
          t[dbi][0][0] = tr16(a0);
          t[dbi][0][1] = tr16(a0 + 1024);
          t[dbi][1][0] = tr16(a0 + 8192);
          t[dbi][1][1] = tr16(a0 + 8192 + 1024);
        }
        asm volatile("s_waitcnt lgkmcnt(0)" ::: "memory");
        __builtin_amdgcn_sched_barrier(0);   // rule #18
#pragma unroll
        for (int dbi = 0; dbi < 2; ++dbi) {
          int db = dbp * 2 + dbi;
          o[db] = __builtin_amdgcn_mfma_f32_16x16x32_bf16(pf0, cat8(t[dbi][0][0], t[dbi][0][1]), o[db], 0, 0, 0);
          o[db] = __builtin_amdgcn_mfma_f32_16x16x32_bf16(pf1, cat8(t[dbi][1][0], t[dbi][1][1]), o[db], 0, 0, 0);
        }
      }

      __syncthreads();   // implicit vmcnt(0): drains STAGE(kt+1); protects buffers
      buf ^= 1;
    } // kt

    // normalize + write ctx[q][h*128+d] bf16
#pragma unroll
    for (int db = 0; db < 8; ++db) {
#pragma unroll
      for (int r = 0; r < 4; ++r) {
        int row = qrow + r;
        int col = h * HD + db * 16 + lo;
        ctx[(size_t)row * HID + col] = f2bf(o[db][r] / l_run[r]);
      }
    }
  } // half
}

// ---------------- launch ----------------

extern "C" void kernel_launch(void* const* d_in, const int* in_sizes, int n_in,
                              void* d_out, int out_size, void* d_ws, size_t ws_size,
                              hipStream_t stream) {
  const float* hidden    = (const float*)d_in[0];
  const int*   pos       = (const int*)d_in[2];
  const float* kb_keys   = (const float*)d_in[3];
  const float* kb_values = (const float*)d_in[4];
  const float* Wq        = (const float*)d_in[5];
  const float* Wq2       = (const float*)d_in[6];
  const float* Wk        = (const float*)d_in[7];
  const float* Wv        = (const float*)d_in[8];
  const float* Wo        = (const float*)d_in[9];
  const float* sshift    = (const float*)d_in[10];
  float* out = (float*)d_out;

  char* ws = (char*)d_ws;
  size_t off = 0;
  auto alloc = [&](size_t bytes) { char* p = ws + off; off += (bytes + 255) & ~(size_t)255; return p; };
  unsigned short* hidden_bf = (unsigned short*)alloc((size_t)QLEN * HID * 2);
  unsigned short* wbuf      = (unsigned short*)alloc((size_t)HID * HID * 2);
  unsigned short* qbf       = (unsigned short*)alloc((size_t)NH * QLEN * HD * 2);
  unsigned short* kallp     = (unsigned short*)alloc((size_t)NH * KVLEN * HD * 2);
  unsigned short* vallp     = (unsigned short*)alloc((size_t)NH * KVLEN * HD * 2);
  unsigned short* ctx       = (unsigned short*)alloc((size_t)QLEN * HID * 2);
  float2*         cs2       = (float2*)alloc((size_t)QLEN * 64 * 8);
  float*          part      = (float*)alloc((size_t)16 * HID * 4);
  float*          hsum      = (float*)alloc(HID * 4);
  float*          qs        = (float*)alloc(HID * 4);
  float*          scores    = (float*)alloc(KBLEN * 4);
  int*            idx       = (int*)alloc(NTOPK * 4);

  dim3 blk(256);

  k_cast<<<QLEN * HID / 4 / 256, blk, 0, stream>>>(hidden, hidden_bf, QLEN * HID / 4);
  k_rowsum_p<<<dim3(HID / 256, 16), blk, 0, stream>>>(hidden, part);
  k_rowsum_r<<<HID / 256, blk, 0, stream>>>(part, hsum);
  k_dotrows<<<HID / 4, blk, 0, stream>>>(hsum, Wq2, qs, HID, 1.0f);
  k_dotrows<<<KBLEN / 4, blk, 0, stream>>>(qs, kb_keys, scores, HID, SCALE);
  k_topk<<<1, KBLEN, 0, stream>>>(scores, idx);
  k_cs<<<QLEN * 64 / 256, blk, 0, stream>>>(pos, cs2);

  dim3 ggrid(HID / 256, QLEN / 128);  // (16, 16) = 256 blocks, 1/CU
  dim3 gblk(512);
  int wcast_blocks = HID * HID / 4 / 256;

  // Q projection + RoPE -> qbf[h][q][d]
  k_cast<<<wcast_blocks, blk, 0, stream>>>(Wq, wbuf, HID * HID / 4);
  gemm_bt<2><<<ggrid, gblk, 0, stream>>>(hidden_bf, wbuf, nullptr, qbf, QLEN, HID, HID, QLEN, 0, cs2);
  // K projection + RoPE -> k_all[h][128+q][d]
  k_cast<<<wcast_blocks, blk, 0, stream>>>(Wk, wbuf, HID * HID / 4);
  gemm_bt<2><<<ggrid, gblk, 0, stream>>>(hidden_bf, wbuf, nullptr, kallp, QLEN, HID, HID, KVLEN, NTOPK, cs2);
  // V projection -> v_all[h][128+q][d]
  k_cast<<<wcast_blocks, blk, 0, stream>>>(Wv, wbuf, HID * HID / 4);
  gemm_bt<1><<<ggrid, gblk, 0, stream>>>(hidden_bf, wbuf, nullptr, vallp, QLEN, HID, HID, KVLEN, NTOPK, cs2);

  // gather selected KB keys/values into k_all/v_all[:, :128]
  k_gather<<<NH * NTOPK * HD / 256, blk, 0, stream>>>(kb_keys, kb_values, idx, kallp, vallp);

  // flash attention -> ctx bf16 [q][h*128+d]
  dim3 agrid(16, NH);
  attn_kernel<<<agrid, blk, 0, stream>>>(qbf, kallp, vallp, sshift, ctx);

  // output projection -> d_out fp32
  k_cast<<<wcast_blocks, blk, 0, stream>>>(Wo, wbuf, HID * HID / 4);
  gemm_bt<0><<<ggrid, gblk, 0, stream>>>(ctx, wbuf, out, nullptr, QLEN, HID, HID, 0, 0, cs2);
}